// Round 1
// baseline (3418.025 us; speedup 1.0000x reference)
//
#include <hip/hip_runtime.h>
#include <math.h>
#include <stdint.h>

typedef __bf16 bf16_t;
typedef __bf16 bf16x8 __attribute__((ext_vector_type(8)));
typedef __bf16 bf16x4 __attribute__((ext_vector_type(4)));
typedef float f32x4 __attribute__((ext_vector_type(4)));

#define NLAYER 6
#define DMODEL 768
#define NHEAD 12
#define DHEAD 64
#define SEQ 512
#define BATCH 8
#define MROWS 4096 /* BATCH*SEQ */
#define DFFN 3072

// ---------- helpers ----------

__device__ inline void async_load16(const void* g, void* lds) {
  // global -> LDS direct (wave-uniform LDS base + lane*16 semantics).
  const __attribute__((address_space(1))) void* gp =
      (const __attribute__((address_space(1))) void*)(uintptr_t)g;
  __attribute__((address_space(3))) void* lp =
      (__attribute__((address_space(3))) void*)(uint32_t)(uintptr_t)lds;
  __builtin_amdgcn_global_load_lds(gp, lp, 16, 0, 0);
}

__device__ inline float wsum(float v) {
#pragma unroll
  for (int o = 32; o > 0; o >>= 1) v += __shfl_xor(v, o, 64);
  return v;
}
__device__ inline float wmax(float v) {
#pragma unroll
  for (int o = 32; o > 0; o >>= 1) v = fmaxf(v, __shfl_xor(v, o, 64));
  return v;
}

__device__ inline float gelu_f(float x) {
  float u = 0.7978845608028654f * (x + 0.044715f * x * x * x);
  return 0.5f * x * (1.0f + tanhf(u));
}

// ---------- GEMM:  C[m,n] = sum_k A[m,k] * B[n,k]  (B is [N,K] row-major) ----------
struct GP {
  const bf16_t* A;
  const bf16_t* B;
  const float* bias;   // [N] or null
  const float* resid;  // f32, ldc layout, or null
  float* outF;         // f32 out or null
  bf16_t* outB;        // bf16 out or null
  int M, N, K;
  int lda, ldb, ldc;               // element strides
  long sAb, sAh, sBb, sBh, sCb, sCh;  // batch strides (elements)
  int hdiv;  // batch z -> (zb = z / hdiv, zh = z % hdiv)
  int act;   // 1 = gelu
};

__global__ __launch_bounds__(256) void gemm_kernel(GP p) {
  __shared__ __align__(16) bf16_t As[128 * 32];
  __shared__ __align__(16) bf16_t Bs[128 * 32];
  const int tid = threadIdx.x;
  const int wave = tid >> 6, lane = tid & 63;
  const int wr = wave >> 1, wc = wave & 1;  // 2x2 waves, 64x64 each
  const int lrow = lane & 15, kq = lane >> 4;
  const int sr = tid >> 2;        // staging row 0..63 per round
  const int sc = (tid & 3) << 3;  // staging col 0,8,16,24
  const int m0 = blockIdx.y * 128;
  const int n0 = blockIdx.x * 128;
  const int zb = (int)blockIdx.z / p.hdiv;
  const int zh = (int)blockIdx.z % p.hdiv;
  const bf16_t* A = p.A + zb * p.sAb + zh * p.sAh;
  const bf16_t* B = p.B + zb * p.sBb + zh * p.sBh;
  const long coff = zb * p.sCb + zh * p.sCh;

  f32x4 acc[4][4] = {};

  for (int k0 = 0; k0 < p.K; k0 += 32) {
    // stage A tile [128][32]
#pragma unroll
    for (int r = 0; r < 2; ++r) {
      const bf16_t* gp = A + (long)(m0 + r * 64 + sr) * p.lda + (k0 + sc);
      async_load16(gp, &As[(r * 64 + wave * 16) * 32]);
    }
    // stage B tile [128][32] (rows are output cols n), guarded for N-partial
#pragma unroll
    for (int r = 0; r < 2; ++r) {
      const int chunk0 = n0 + r * 64 + wave * 16;  // wave-uniform
      if (chunk0 + 16 <= p.N) {
        const bf16_t* gp = B + (long)(n0 + r * 64 + sr) * p.ldb + (k0 + sc);
        async_load16(gp, &Bs[(r * 64 + wave * 16) * 32]);
      } else {
        const int brow = n0 + r * 64 + sr;
        bf16x8 z = {};
        if (brow < p.N) z = *(const bf16x8*)(B + (long)brow * p.ldb + (k0 + sc));
        *(bf16x8*)&Bs[(r * 64 + sr) * 32 + sc] = z;
      }
    }
    __syncthreads();

    bf16x8 af[4], bfr[4];
#pragma unroll
    for (int i = 0; i < 4; ++i)
      af[i] = *(const bf16x8*)&As[(wr * 64 + i * 16 + lrow) * 32 + kq * 8];
#pragma unroll
    for (int j = 0; j < 4; ++j)
      bfr[j] = *(const bf16x8*)&Bs[(wc * 64 + j * 16 + lrow) * 32 + kq * 8];
#pragma unroll
    for (int i = 0; i < 4; ++i)
#pragma unroll
      for (int j = 0; j < 4; ++j)
        acc[i][j] = __builtin_amdgcn_mfma_f32_16x16x32_bf16(af[i], bfr[j], acc[i][j], 0, 0, 0);
    __syncthreads();
  }

  float* outF = p.outF ? p.outF + coff : nullptr;
  bf16_t* outB = p.outB ? p.outB + coff : nullptr;
  const float* resid = p.resid ? p.resid + coff : nullptr;
  // C/D layout: col = lane&15, row = (lane>>4)*4 + reg   [m89-verified]
  const int crow0 = m0 + wr * 64 + kq * 4;
  const int ccol0 = n0 + wc * 64 + lrow;
#pragma unroll
  for (int j = 0; j < 4; ++j) {
    const int col = ccol0 + j * 16;
    if (col < p.N) {
#pragma unroll
      for (int i = 0; i < 4; ++i) {
#pragma unroll
        for (int r = 0; r < 4; ++r) {
          const int row = crow0 + i * 16 + r;
          const long idx = (long)row * p.ldc + col;
          float y = acc[i][j][r];
          if (p.bias) y += p.bias[col];
          if (resid) y += resid[idx];
          if (p.act) y = gelu_f(y);
          if (outF) outF[idx] = y;
          if (outB) outB[idx] = (bf16_t)y;
        }
      }
    }
  }
}

// ---------- LayerNorm (row = 768) ----------
__global__ __launch_bounds__(256) void ln_kernel(const float* __restrict__ X,
                                                 const float* __restrict__ g,
                                                 const float* __restrict__ b,
                                                 bf16_t* __restrict__ outB,
                                                 float* __restrict__ outF) {
  const int row = blockIdx.x, tid = threadIdx.x;
  const float* xr = X + (long)row * DMODEL;
  const float v0 = xr[tid], v1 = xr[tid + 256], v2 = xr[tid + 512];
  __shared__ float r1[4], r2[4];
  const int wv = tid >> 6, ln = tid & 63;
  float s = wsum(v0 + v1 + v2);
  if (ln == 0) r1[wv] = s;
  __syncthreads();
  const float mean = (r1[0] + r1[1] + r1[2] + r1[3]) * (1.0f / DMODEL);
  const float d0 = v0 - mean, d1 = v1 - mean, d2 = v2 - mean;
  float q = wsum(d0 * d0 + d1 * d1 + d2 * d2);
  if (ln == 0) r2[wv] = q;
  __syncthreads();
  const float var = (r2[0] + r2[1] + r2[2] + r2[3]) * (1.0f / DMODEL);
  const float rs = rsqrtf(var + 1e-6f);
  const float y0 = d0 * rs * g[tid] + b[tid];
  const float y1 = d1 * rs * g[tid + 256] + b[tid + 256];
  const float y2 = d2 * rs * g[tid + 512] + b[tid + 512];
  const long base = (long)row * DMODEL;
  if (outB) {
    outB[base + tid] = (bf16_t)y0;
    outB[base + tid + 256] = (bf16_t)y1;
    outB[base + tid + 512] = (bf16_t)y2;
  }
  if (outF) {
    outF[base + tid] = y0;
    outF[base + tid + 256] = y1;
    outF[base + tid + 512] = y2;
  }
}

// ---------- embedding * sqrt(D) + sinusoidal PE ----------
__global__ __launch_bounds__(256) void emb_kernel(const int* __restrict__ tgt,
                                                  const float* __restrict__ tab,
                                                  float* __restrict__ res) {
  const int row = blockIdx.x;
  const int t = row & (SEQ - 1);
  const long tok = tgt[row];
  const float* er = tab + tok * DMODEL;
  float* orow = res + (long)row * DMODEL;
  const float c1 = -9.210340371976184f / 768.0f;  // -ln(10000)/D
  for (int c = threadIdx.x; c < DMODEL; c += 256) {
    const float e = er[c] * 27.712812921102035f;  // sqrt(768)
    const float div = expf((float)(c & ~1) * c1);
    const float ang = (float)t * div;
    const float pe = (c & 1) ? cosf(ang) : sinf(ang);
    orow[c] = e + pe;
  }
}

// ---------- masked softmax over rows of SP [bh][q][k], in place, bf16 ----------
__global__ __launch_bounds__(64) void softmax_kernel(bf16_t* __restrict__ SP,
                                                     const int* __restrict__ toks,
                                                     int causal) {
  const long row = blockIdx.x;  // bh*512 + q
  const int q = (int)(row & (SEQ - 1));
  const int bh = (int)(row >> 9);
  const int b = bh / NHEAD;
  bf16_t* rp = SP + row * SEQ;
  const int lane = threadIdx.x;
  const bf16x8 sv = *(const bf16x8*)(rp + lane * 8);
  const int* tb = toks + b * SEQ;
  float s[8];
  float m = -3.0e38f;
#pragma unroll
  for (int j = 0; j < 8; ++j) {
    const int k = lane * 8 + j;
    const float x = (float)sv[j] * 0.125f;  // fold 1/sqrt(DH)
    const bool masked = (tb[k] == 0) || (causal && (k > q));
    s[j] = masked ? -1.0e18f : x;
    m = fmaxf(m, s[j]);
  }
  m = wmax(m);
  float sum = 0.0f;
#pragma unroll
  for (int j = 0; j < 8; ++j) {
    const float pexp = expf(s[j] - m);
    s[j] = pexp;
    sum += pexp;
  }
  sum = wsum(sum);
  const float inv = 1.0f / sum;
  bf16x8 o;
#pragma unroll
  for (int j = 0; j < 8; ++j) o[j] = (bf16_t)(s[j] * inv);
  *(bf16x8*)(rp + lane * 8) = o;
}

// ---------- V transpose: Vt[bh][dh][k] = qkv[b*512+k][1536 + h*64 + dh] ----------
__global__ __launch_bounds__(256) void vtrans_kernel(const bf16_t* __restrict__ qkv,
                                                     bf16_t* __restrict__ Vt) {
  __shared__ bf16_t t[64][66];
  const int bh = blockIdx.y, b = bh / NHEAD, h = bh % NHEAD;
  const int k0 = blockIdx.x * 64;
  const int tx = threadIdx.x & 63, ty = threadIdx.x >> 6;
  const bf16_t* src = qkv + 2 * DMODEL + h * DHEAD;
#pragma unroll
  for (int kk = ty; kk < 64; kk += 4)
    t[tx][kk] = src[(long)(b * SEQ + k0 + kk) * (3 * DMODEL) + tx];
  __syncthreads();
#pragma unroll
  for (int dd = ty; dd < 64; dd += 4)
    Vt[((long)bh * DHEAD + dd) * SEQ + k0 + tx] = t[dd][tx];
}

// ---------- f32 -> bf16 convert (n4 = n/4) ----------
__global__ __launch_bounds__(256) void cvt_kernel(const float* __restrict__ in,
                                                  bf16_t* __restrict__ o, int n4) {
  const int i = blockIdx.x * 256 + threadIdx.x;
  if (i < n4) {
    const float4 v = ((const float4*)in)[i];
    bf16x4 r = {(bf16_t)v.x, (bf16_t)v.y, (bf16_t)v.z, (bf16_t)v.w};
    ((bf16x4*)o)[i] = r;
  }
}

// ---------- host ----------
extern "C" void kernel_launch(void* const* d_in, const int* in_sizes, int n_in,
                              void* d_out, int out_size, void* d_ws, size_t ws_size,
                              hipStream_t stream) {
  (void)in_sizes; (void)n_in; (void)out_size; (void)ws_size;
  const int* tgt = (const int*)d_in[0];
  const int* srct = (const int*)d_in[1];
  const float* memb = (const float*)d_in[2];
  const float* embt = (const float*)d_in[3];
  const float* sa_w = (const float*)d_in[4];
  const float* sa_b = (const float*)d_in[5];
  const float* ca_w = (const float*)d_in[6];
  const float* ca_b = (const float*)d_in[7];
  const float* ln_g = (const float*)d_in[8];
  const float* ln_b = (const float*)d_in[9];
  const float* ff_w1 = (const float*)d_in[10];
  const float* ff_b1 = (const float*)d_in[11];
  const float* ff_w2 = (const float*)d_in[12];
  const float* ff_b2 = (const float*)d_in[13];
  const float* out_g = (const float*)d_in[14];
  const float* out_b = (const float*)d_in[15];
  float* out = (float*)d_out;

  char* wsb = (char*)d_ws;
  size_t off = 0;
  auto alloc = [&](size_t bytes) -> void* {
    void* pp = wsb + off;
    off = (off + bytes + 255) & ~(size_t)255;
    return pp;
  };
  float* res = (float*)alloc((size_t)MROWS * DMODEL * 4);            // fp32 residual stream
  bf16_t* xb = (bf16_t*)alloc((size_t)MROWS * DMODEL * 2);           // LN output
  bf16_t* qkvb = (bf16_t*)alloc((size_t)MROWS * 3 * DMODEL * 2);     // fused q|k|v
  bf16_t* ctxb = (bf16_t*)alloc((size_t)MROWS * DMODEL * 2);
  bf16_t* membb = (bf16_t*)alloc((size_t)MROWS * DMODEL * 2);        // memory bank bf16
  bf16_t* Vt = (bf16_t*)alloc((size_t)BATCH * NHEAD * DHEAD * SEQ * 2);
  bf16_t* SP = (bf16_t*)alloc((size_t)BATCH * NHEAD * SEQ * SEQ * 2);  // scores/probs
  bf16_t* ffh = (bf16_t*)alloc((size_t)MROWS * DFFN * 2);
  bf16_t* wA = (bf16_t*)alloc((size_t)4 * DMODEL * DMODEL * 2);      // per-layer attn weights
  bf16_t* wF1 = (bf16_t*)alloc((size_t)DFFN * DMODEL * 2);
  bf16_t* wF2 = (bf16_t*)alloc((size_t)DFFN * DMODEL * 2);

  auto gemm = [&](const bf16_t* A, const bf16_t* Bm, const float* bias,
                  const float* resid, float* oF, bf16_t* oB, int M, int N, int K,
                  int lda, int ldb, int ldc, int nb, long sAb, long sAh, long sBb,
                  long sBh, long sCb, long sCh, int hdiv, int act) {
    GP p{A, Bm, bias, resid, oF, oB, M, N, K, lda, ldb, ldc,
         sAb, sAh, sBb, sBh, sCb, sCh, hdiv, act};
    dim3 g((unsigned)((N + 127) / 128), (unsigned)(M / 128), (unsigned)nb);
    gemm_kernel<<<g, 256, 0, stream>>>(p);
  };

  const long WSZ = (long)DMODEL * DMODEL;  // 589824
  const long SPh = (long)SEQ * SEQ;        // 262144
  const long sRow3 = (long)SEQ * 3 * DMODEL;

  emb_kernel<<<MROWS, 256, 0, stream>>>(tgt, embt, res);
  cvt_kernel<<<(MROWS * DMODEL / 4 + 255) / 256, 256, 0, stream>>>(memb, membb,
                                                                   MROWS * DMODEL / 4);

  for (int l = 0; l < NLAYER; ++l) {
    const float* saw = sa_w + (long)l * 4 * WSZ;
    const float* sab = sa_b + (long)l * 4 * DMODEL;
    const float* caw = ca_w + (long)l * 4 * WSZ;
    const float* cab = ca_b + (long)l * 4 * DMODEL;

    // ======== self-attention ========
    ln_kernel<<<MROWS, 256, 0, stream>>>(res, ln_g + (l * 3 + 0) * DMODEL,
                                         ln_b + (l * 3 + 0) * DMODEL, xb, nullptr);
    cvt_kernel<<<(int)((WSZ + 255) / 256), 256, 0, stream>>>(saw, wA, (int)WSZ);  // 4 mats
    // fused QKV: N = 2304
    gemm(xb, wA, sab, nullptr, nullptr, qkvb, MROWS, 3 * DMODEL, DMODEL,
         DMODEL, DMODEL, 3 * DMODEL, 1, 0, 0, 0, 0, 0, 0, 1, 0);
    vtrans_kernel<<<dim3(SEQ / 64, BATCH * NHEAD), 256, 0, stream>>>(qkvb, Vt);
    // scores: per head, [512x512] = Q x K^T, K=64
    gemm(qkvb, qkvb + DMODEL, nullptr, nullptr, nullptr, SP, SEQ, SEQ, DHEAD,
         3 * DMODEL, 3 * DMODEL, SEQ, BATCH * NHEAD,
         sRow3, DHEAD, sRow3, DHEAD, (long)NHEAD * SPh, SPh, NHEAD, 0);
    softmax_kernel<<<BATCH * NHEAD * SEQ, 64, 0, stream>>>(SP, tgt, 1);
    // ctx: P x V  (B = Vt [64][512])
    gemm(SP, Vt, nullptr, nullptr, nullptr, ctxb, SEQ, DHEAD, SEQ,
         SEQ, SEQ, DMODEL, BATCH * NHEAD,
         (long)NHEAD * SPh, SPh, (long)NHEAD * DHEAD * SEQ, (long)DHEAD * SEQ,
         (long)SEQ * DMODEL, DHEAD, NHEAD, 0);
    // out proj + residual (in-place fp32)
    gemm(ctxb, wA + 3 * WSZ, sab + 3 * DMODEL, res, res, nullptr, MROWS, DMODEL,
         DMODEL, DMODEL, DMODEL, DMODEL, 1, 0, 0, 0, 0, 0, 0, 1, 0);

    // ======== cross-attention ========
    ln_kernel<<<MROWS, 256, 0, stream>>>(res, ln_g + (l * 3 + 1) * DMODEL,
                                         ln_b + (l * 3 + 1) * DMODEL, xb, nullptr);
    cvt_kernel<<<(int)((WSZ + 255) / 256), 256, 0, stream>>>(caw, wA, (int)WSZ);
    gemm(xb, wA, cab, nullptr, nullptr, qkvb, MROWS, DMODEL, DMODEL,
         DMODEL, DMODEL, 3 * DMODEL, 1, 0, 0, 0, 0, 0, 0, 1, 0);  // q -> cols 0..767
    gemm(membb, wA + WSZ, cab + DMODEL, nullptr, nullptr, qkvb + DMODEL, MROWS,
         2 * DMODEL, DMODEL, DMODEL, DMODEL, 3 * DMODEL, 1, 0, 0, 0, 0, 0, 0, 1, 0);  // k,v
    vtrans_kernel<<<dim3(SEQ / 64, BATCH * NHEAD), 256, 0, stream>>>(qkvb, Vt);
    gemm(qkvb, qkvb + DMODEL, nullptr, nullptr, nullptr, SP, SEQ, SEQ, DHEAD,
         3 * DMODEL, 3 * DMODEL, SEQ, BATCH * NHEAD,
         sRow3, DHEAD, sRow3, DHEAD, (long)NHEAD * SPh, SPh, NHEAD, 0);
    softmax_kernel<<<BATCH * NHEAD * SEQ, 64, 0, stream>>>(SP, srct, 0);
    gemm(SP, Vt, nullptr, nullptr, nullptr, ctxb, SEQ, DHEAD, SEQ,
         SEQ, SEQ, DMODEL, BATCH * NHEAD,
         (long)NHEAD * SPh, SPh, (long)NHEAD * DHEAD * SEQ, (long)DHEAD * SEQ,
         (long)SEQ * DMODEL, DHEAD, NHEAD, 0);
    gemm(ctxb, wA + 3 * WSZ, cab + 3 * DMODEL, res, res, nullptr, MROWS, DMODEL,
         DMODEL, DMODEL, DMODEL, DMODEL, 1, 0, 0, 0, 0, 0, 0, 1, 0);

    // ======== FFN ========
    ln_kernel<<<MROWS, 256, 0, stream>>>(res, ln_g + (l * 3 + 2) * DMODEL,
                                         ln_b + (l * 3 + 2) * DMODEL, xb, nullptr);
    cvt_kernel<<<(int)((DFFN * (long)DMODEL / 4 + 255) / 256), 256, 0, stream>>>(
        ff_w1 + (long)l * DFFN * DMODEL, wF1, (int)(DFFN * (long)DMODEL / 4));
    cvt_kernel<<<(int)((DFFN * (long)DMODEL / 4 + 255) / 256), 256, 0, stream>>>(
        ff_w2 + (long)l * DFFN * DMODEL, wF2, (int)(DFFN * (long)DMODEL / 4));
    gemm(xb, wF1, ff_b1 + (long)l * DFFN, nullptr, nullptr, ffh, MROWS, DFFN,
         DMODEL, DMODEL, DMODEL, DFFN, 1, 0, 0, 0, 0, 0, 0, 1, 1);  // gelu
    gemm(ffh, wF2, ff_b2 + (long)l * DMODEL, res, res, nullptr, MROWS, DMODEL,
         DFFN, DFFN, DFFN, DMODEL, 1, 0, 0, 0, 0, 0, 0, 1, 0);
  }

  ln_kernel<<<MROWS, 256, 0, stream>>>(res, out_g, out_b, nullptr, out);
}

// Round 2
// 3236.724 us; speedup vs baseline: 1.0560x; 1.0560x over previous
//
#include <hip/hip_runtime.h>
#include <math.h>
#include <stdint.h>

typedef __bf16 bf16_t;
typedef __bf16 bf16x8 __attribute__((ext_vector_type(8)));
typedef __bf16 bf16x4 __attribute__((ext_vector_type(4)));
typedef float f32x4 __attribute__((ext_vector_type(4)));

#define NLAYER 6
#define DMODEL 768
#define NHEAD 12
#define DHEAD 64
#define SEQ 512
#define BATCH 8
#define MROWS 4096 /* BATCH*SEQ */
#define DFFN 3072

// ---------- helpers ----------

__device__ inline void async_load16(const void* g, void* lds) {
  const __attribute__((address_space(1))) void* gp =
      (const __attribute__((address_space(1))) void*)(uintptr_t)g;
  __attribute__((address_space(3))) void* lp =
      (__attribute__((address_space(3))) void*)(uint32_t)(uintptr_t)lds;
  __builtin_amdgcn_global_load_lds(gp, lp, 16, 0, 0);
}

__device__ inline float wsum(float v) {
#pragma unroll
  for (int o = 32; o > 0; o >>= 1) v += __shfl_xor(v, o, 64);
  return v;
}

__device__ inline float gelu_f(float x) {
  float u = 0.7978845608028654f * (x + 0.044715f * x * x * x);
  return 0.5f * x * (1.0f + tanhf(u));
}

// ---------- GEMM:  C[m,n] = sum_k A[m,k] * B[n,k]  (B is [N,K] row-major) ----------
struct GP {
  const bf16_t* A;
  const bf16_t* B;
  const float* bias;   // [N] or null
  const float* resid;  // f32, ldc layout, or null
  float* outF;         // f32 out or null
  bf16_t* outB;        // bf16 out or null
  int M, N, K;
  int lda, ldb, ldc;
  long sAb, sAh, sBb, sBh, sCb, sCh;
  int hdiv;
  int act;     // 1 = gelu
  int ksplit;  // >1: partial-K, atomicAdd into outF (bias added by split 0)
};

__global__ __launch_bounds__(256) void gemm_kernel(GP p) {
  __shared__ __align__(16) bf16_t As[128 * 32];
  __shared__ __align__(16) bf16_t Bs[128 * 32];
  const int tid = threadIdx.x;
  const int wave = tid >> 6, lane = tid & 63;
  const int wr = wave >> 1, wc = wave & 1;
  const int lrow = lane & 15, kq = lane >> 4;
  const int sr = tid >> 2;
  const int sc = (tid & 3) << 3;
  const int m0 = blockIdx.y * 128;
  const int n0 = blockIdx.x * 128;
  int zs = 0, zz = (int)blockIdx.z;
  if (p.ksplit > 1) { zs = zz; zz = 0; }
  const int zb = zz / p.hdiv;
  const int zh = zz % p.hdiv;
  const bf16_t* A = p.A + zb * p.sAb + zh * p.sAh;
  const bf16_t* B = p.B + zb * p.sBb + zh * p.sBh;
  const long coff = zb * p.sCb + zh * p.sCh;

  const int kc = p.K / p.ksplit;
  const int kstart = zs * kc;

  f32x4 acc[4][4] = {};

  for (int k0 = kstart; k0 < kstart + kc; k0 += 32) {
#pragma unroll
    for (int r = 0; r < 2; ++r) {
      const bf16_t* gp = A + (long)(m0 + r * 64 + sr) * p.lda + (k0 + sc);
      async_load16(gp, &As[(r * 64 + wave * 16) * 32]);
    }
#pragma unroll
    for (int r = 0; r < 2; ++r) {
      const int chunk0 = n0 + r * 64 + wave * 16;
      if (chunk0 + 16 <= p.N) {
        const bf16_t* gp = B + (long)(n0 + r * 64 + sr) * p.ldb + (k0 + sc);
        async_load16(gp, &Bs[(r * 64 + wave * 16) * 32]);
      } else {
        const int brow = n0 + r * 64 + sr;
        bf16x8 z = {};
        if (brow < p.N) z = *(const bf16x8*)(B + (long)brow * p.ldb + (k0 + sc));
        *(bf16x8*)&Bs[(r * 64 + sr) * 32 + sc] = z;
      }
    }
    __syncthreads();

    bf16x8 af[4], bfr[4];
#pragma unroll
    for (int i = 0; i < 4; ++i)
      af[i] = *(const bf16x8*)&As[(wr * 64 + i * 16 + lrow) * 32 + kq * 8];
#pragma unroll
    for (int j = 0; j < 4; ++j)
      bfr[j] = *(const bf16x8*)&Bs[(wc * 64 + j * 16 + lrow) * 32 + kq * 8];
#pragma unroll
    for (int i = 0; i < 4; ++i)
#pragma unroll
      for (int j = 0; j < 4; ++j)
        acc[i][j] = __builtin_amdgcn_mfma_f32_16x16x32_bf16(af[i], bfr[j], acc[i][j], 0, 0, 0);
    __syncthreads();
  }

  float* outF = p.outF ? p.outF + coff : nullptr;
  bf16_t* outB = p.outB ? p.outB + coff : nullptr;
  const float* resid = p.resid ? p.resid + coff : nullptr;
  const int crow0 = m0 + wr * 64 + kq * 4;
  const int ccol0 = n0 + wc * 64 + lrow;
#pragma unroll
  for (int j = 0; j < 4; ++j) {
    const int col = ccol0 + j * 16;
    if (col < p.N) {
#pragma unroll
      for (int i = 0; i < 4; ++i) {
#pragma unroll
        for (int r = 0; r < 4; ++r) {
          const int row = crow0 + i * 16 + r;
          const long idx = (long)row * p.ldc + col;
          float y = acc[i][j][r];
          if (p.ksplit > 1) {
            if (zs == 0 && p.bias) y += p.bias[col];
            atomicAdd(&outF[idx], y);
          } else {
            if (p.bias) y += p.bias[col];
            if (resid) y += resid[idx];
            if (p.act) y = gelu_f(y);
            if (outF) outF[idx] = y;
            if (outB) outB[idx] = (bf16_t)y;
          }
        }
      }
    }
  }
}

// ---------- fused flash attention ----------
// qkv: [B*SEQ][3*DMODEL] rows = tokens; Q at col h*64, K at 768+h*64, V at 1536+h*64
// ctx: [B*SEQ][DMODEL] bf16 out. toks: mask tokens for KEYS. causal: k>q masked.
#define QT 64
#define KT 128
#define VPAD 136

__global__ __launch_bounds__(256) void attn_kernel(const bf16_t* __restrict__ qkv,
                                                   const int* __restrict__ toks,
                                                   bf16_t* __restrict__ ctx, int causal) {
  __shared__ __align__(16) bf16_t Qs[QT * 64];
  __shared__ __align__(16) bf16_t Ks[KT * 64];
  __shared__ __align__(16) bf16_t Vs[64 * VPAD];
  __shared__ __align__(16) bf16_t Ps[QT * VPAD];
  __shared__ int Ts[SEQ];
  const int tid = threadIdx.x;
  const int wave = tid >> 6, lane = tid & 63;
  const int lm = lane & 15, lq = lane >> 4;
  const int q0 = blockIdx.x * QT;
  const int bh = blockIdx.y;
  const int b = bh / NHEAD, h = bh % NHEAD;
  const long rowbase = (long)b * SEQ;
  const int LD = 3 * DMODEL;
  const bf16_t* Qg = qkv + (rowbase + q0) * LD + h * DHEAD;
  const bf16_t* Kg = qkv + rowbase * LD + DMODEL + h * DHEAD;
  const bf16_t* Vg = qkv + rowbase * LD + 2 * DMODEL + h * DHEAD;

  Ts[tid] = toks[b * SEQ + tid];
  Ts[tid + 256] = toks[b * SEQ + tid + 256];

  // stage Q tile (64 x 64), 2 async rounds, LDS addr = chunk*16B (contiguous)
#pragma unroll
  for (int r = 0; r < 2; ++r) {
    const int c = r * 256 + tid;
    const int row = c >> 3, c8 = (c & 7) * 8;
    async_load16(Qg + (long)row * LD + c8, &Qs[c * 8]);
  }
  __syncthreads();

  bf16x8 aQ0 = *(const bf16x8*)&Qs[(wave * 16 + lm) * 64 + lq * 8];
  bf16x8 aQ1 = *(const bf16x8*)&Qs[(wave * 16 + lm) * 64 + 32 + lq * 8];

  float m_i[4], l_i[4];
  f32x4 O[4] = {};
#pragma unroll
  for (int r = 0; r < 4; ++r) { m_i[r] = -3.0e38f; l_i[r] = 0.0f; }

  const int s_end = causal ? (q0 + QT) : SEQ;
  for (int s0 = 0; s0 < s_end; s0 += KT) {
    __syncthreads();  // prior iter's Ks/Vs reads complete
    // stage K tile (128 x 64), 4 async rounds
#pragma unroll
    for (int r = 0; r < 4; ++r) {
      const int c = r * 256 + tid;
      const int row = c >> 3, c8 = (c & 7) * 8;
      async_load16(Kg + (long)(s0 + row) * LD + c8, &Ks[c * 8]);
    }
    // stage V transposed: Vs[d][s]
#pragma unroll
    for (int r = 0; r < 4; ++r) {
      const int c = r * 256 + tid;
      const int row = c >> 3, c8 = (c & 7) * 8;
      const bf16x8 vv = *(const bf16x8*)(Vg + (long)(s0 + row) * LD + c8);
#pragma unroll
      for (int j = 0; j < 8; ++j) Vs[(c8 + j) * VPAD + row] = vv[j];
    }
    __syncthreads();  // Ks/Vs ready

    // S = Q K^T for this wave's 16 q-rows x 128 k-cols
    f32x4 sv[8];
#pragma unroll
    for (int jt = 0; jt < 8; ++jt) {
      const bf16x8 b0 = *(const bf16x8*)&Ks[(jt * 16 + lm) * 64 + lq * 8];
      const bf16x8 b1 = *(const bf16x8*)&Ks[(jt * 16 + lm) * 64 + 32 + lq * 8];
      f32x4 a = {};
      a = __builtin_amdgcn_mfma_f32_16x16x32_bf16(aQ0, b0, a, 0, 0, 0);
      a = __builtin_amdgcn_mfma_f32_16x16x32_bf16(aQ1, b1, a, 0, 0, 0);
      sv[jt] = a;
    }

    // online softmax per q-row (row = lq*4 + r within wave band)
#pragma unroll
    for (int r = 0; r < 4; ++r) {
      const int qa = q0 + wave * 16 + lq * 4 + r;
      float sr[8];
      float mx = -3.0e38f;
#pragma unroll
      for (int jt = 0; jt < 8; ++jt) {
        const int k = s0 + jt * 16 + lm;
        const float x = sv[jt][r] * 0.125f;  // 1/sqrt(64)
        const bool msk = (Ts[k] == 0) || (causal && (k > qa));
        sr[jt] = msk ? -1.0e18f : x;
        mx = fmaxf(mx, sr[jt]);
      }
#pragma unroll
      for (int o = 1; o < 16; o <<= 1) mx = fmaxf(mx, __shfl_xor(mx, o, 64));
      const float mn = fmaxf(m_i[r], mx);
      const float alpha = __expf(m_i[r] - mn);
      float sum = 0.0f;
#pragma unroll
      for (int jt = 0; jt < 8; ++jt) {
        const float pv = __expf(sr[jt] - mn);
        sr[jt] = pv;
        sum += pv;
      }
#pragma unroll
      for (int o = 1; o < 16; o <<= 1) sum += __shfl_xor(sum, o, 64);
      l_i[r] = l_i[r] * alpha + sum;
      m_i[r] = mn;
#pragma unroll
      for (int jn = 0; jn < 4; ++jn) O[jn][r] *= alpha;
#pragma unroll
      for (int jt = 0; jt < 8; ++jt)
        Ps[(wave * 16 + lq * 4 + r) * VPAD + jt * 16 + lm] = (bf16_t)sr[jt];
    }

    // O += P V   (wave-private Ps region; no cross-wave barrier needed)
#pragma unroll
    for (int kt = 0; kt < 4; ++kt) {
      const bf16x8 aP = *(const bf16x8*)&Ps[(wave * 16 + lm) * VPAD + kt * 32 + lq * 8];
#pragma unroll
      for (int jn = 0; jn < 4; ++jn) {
        const bf16x8 bV = *(const bf16x8*)&Vs[(jn * 16 + lm) * VPAD + kt * 32 + lq * 8];
        O[jn] = __builtin_amdgcn_mfma_f32_16x16x32_bf16(aP, bV, O[jn], 0, 0, 0);
      }
    }
  }

  // epilogue: normalize and store
#pragma unroll
  for (int r = 0; r < 4; ++r) {
    const int q = q0 + wave * 16 + lq * 4 + r;
    const float inv = 1.0f / l_i[r];
#pragma unroll
    for (int jn = 0; jn < 4; ++jn) {
      const int d = jn * 16 + lm;
      ctx[(rowbase + q) * DMODEL + h * DHEAD + d] = (bf16_t)(O[jn][r] * inv);
    }
  }
}

// ---------- LayerNorm (row = 768) ----------
__global__ __launch_bounds__(256) void ln_kernel(const float* __restrict__ X,
                                                 const float* __restrict__ g,
                                                 const float* __restrict__ b,
                                                 bf16_t* __restrict__ outB,
                                                 float* __restrict__ outF) {
  const int row = blockIdx.x, tid = threadIdx.x;
  const float* xr = X + (long)row * DMODEL;
  const float v0 = xr[tid], v1 = xr[tid + 256], v2 = xr[tid + 512];
  __shared__ float r1[4], r2[4];
  const int wv = tid >> 6, ln = tid & 63;
  float s = wsum(v0 + v1 + v2);
  if (ln == 0) r1[wv] = s;
  __syncthreads();
  const float mean = (r1[0] + r1[1] + r1[2] + r1[3]) * (1.0f / DMODEL);
  const float d0 = v0 - mean, d1 = v1 - mean, d2 = v2 - mean;
  float q = wsum(d0 * d0 + d1 * d1 + d2 * d2);
  if (ln == 0) r2[wv] = q;
  __syncthreads();
  const float var = (r2[0] + r2[1] + r2[2] + r2[3]) * (1.0f / DMODEL);
  const float rs = rsqrtf(var + 1e-6f);
  const float y0 = d0 * rs * g[tid] + b[tid];
  const float y1 = d1 * rs * g[tid + 256] + b[tid + 256];
  const float y2 = d2 * rs * g[tid + 512] + b[tid + 512];
  const long base = (long)row * DMODEL;
  if (outB) {
    outB[base + tid] = (bf16_t)y0;
    outB[base + tid + 256] = (bf16_t)y1;
    outB[base + tid + 512] = (bf16_t)y2;
  }
  if (outF) {
    outF[base + tid] = y0;
    outF[base + tid + 256] = y1;
    outF[base + tid + 512] = y2;
  }
}

// ---------- embedding * sqrt(D) + sinusoidal PE ----------
__global__ __launch_bounds__(256) void emb_kernel(const int* __restrict__ tgt,
                                                  const float* __restrict__ tab,
                                                  float* __restrict__ res) {
  const int row = blockIdx.x;
  const int t = row & (SEQ - 1);
  const long tok = tgt[row];
  const float* er = tab + tok * DMODEL;
  float* orow = res + (long)row * DMODEL;
  const float c1 = -9.210340371976184f / 768.0f;
  for (int c = threadIdx.x; c < DMODEL; c += 256) {
    const float e = er[c] * 27.712812921102035f;
    const float div = expf((float)(c & ~1) * c1);
    const float ang = (float)t * div;
    const float pe = (c & 1) ? cosf(ang) : sinf(ang);
    orow[c] = e + pe;
  }
}

// ---------- f32 -> bf16 convert (n4 = n/4) ----------
__global__ __launch_bounds__(256) void cvt_kernel(const float* __restrict__ in,
                                                  bf16_t* __restrict__ o, int n4) {
  const int i = blockIdx.x * 256 + threadIdx.x;
  if (i < n4) {
    const float4 v = ((const float4*)in)[i];
    bf16x4 r = {(bf16_t)v.x, (bf16_t)v.y, (bf16_t)v.z, (bf16_t)v.w};
    ((bf16x4*)o)[i] = r;
  }
}

// ---------- strided f32[4096x768] -> bf16 into qkv stride 2304 (cols 0..767) ----------
__global__ __launch_bounds__(256) void cvt2d_kernel(const float* __restrict__ in,
                                                    bf16_t* __restrict__ o) {
  const int row = blockIdx.x, tid = threadIdx.x;
  const long ib = (long)row * DMODEL;
  const long ob = (long)row * 3 * DMODEL;
  o[ob + tid] = (bf16_t)in[ib + tid];
  o[ob + tid + 256] = (bf16_t)in[ib + tid + 256];
  o[ob + tid + 512] = (bf16_t)in[ib + tid + 512];
}

// ---------- zero fill (float4 granules) ----------
__global__ __launch_bounds__(256) void zero_kernel(float4* __restrict__ p, int n4) {
  const int i = blockIdx.x * 256 + threadIdx.x;
  if (i < n4) p[i] = float4{0.0f, 0.0f, 0.0f, 0.0f};
}

// ---------- host ----------
extern "C" void kernel_launch(void* const* d_in, const int* in_sizes, int n_in,
                              void* d_out, int out_size, void* d_ws, size_t ws_size,
                              hipStream_t stream) {
  (void)in_sizes; (void)n_in; (void)out_size; (void)ws_size;
  const int* tgt = (const int*)d_in[0];
  const int* srct = (const int*)d_in[1];
  const float* memb = (const float*)d_in[2];
  const float* embt = (const float*)d_in[3];
  const float* sa_w = (const float*)d_in[4];
  const float* sa_b = (const float*)d_in[5];
  const float* ca_w = (const float*)d_in[6];
  const float* ca_b = (const float*)d_in[7];
  const float* ln_g = (const float*)d_in[8];
  const float* ln_b = (const float*)d_in[9];
  const float* ff_w1 = (const float*)d_in[10];
  const float* ff_b1 = (const float*)d_in[11];
  const float* ff_w2 = (const float*)d_in[12];
  const float* ff_b2 = (const float*)d_in[13];
  const float* out_g = (const float*)d_in[14];
  const float* out_b = (const float*)d_in[15];
  float* out = (float*)d_out;

  char* wsb = (char*)d_ws;
  size_t off = 0;
  auto alloc = [&](size_t bytes) -> void* {
    void* pp = wsb + off;
    off = (off + bytes + 255) & ~(size_t)255;
    return pp;
  };
  float* res = (float*)alloc((size_t)MROWS * DMODEL * 4);
  float* qf = (float*)alloc((size_t)MROWS * DMODEL * 4);  // CA-q f32 accumulator
  bf16_t* xb = (bf16_t*)alloc((size_t)MROWS * DMODEL * 2);
  bf16_t* qkvb = (bf16_t*)alloc((size_t)MROWS * 3 * DMODEL * 2);
  bf16_t* ctxb = (bf16_t*)alloc((size_t)MROWS * DMODEL * 2);
  bf16_t* membb = (bf16_t*)alloc((size_t)MROWS * DMODEL * 2);
  bf16_t* ffh = (bf16_t*)alloc((size_t)MROWS * DFFN * 2);
  bf16_t* wA = (bf16_t*)alloc((size_t)4 * DMODEL * DMODEL * 2);
  bf16_t* wF1 = (bf16_t*)alloc((size_t)DFFN * DMODEL * 2);
  bf16_t* wF2 = (bf16_t*)alloc((size_t)DFFN * DMODEL * 2);

  auto gemm = [&](const bf16_t* A, const bf16_t* Bm, const float* bias,
                  const float* resid, float* oF, bf16_t* oB, int M, int N, int K,
                  int lda, int ldb, int ldc, int nb, long sAb, long sAh, long sBb,
                  long sBh, long sCb, long sCh, int hdiv, int act, int ksplit) {
    GP p{A, Bm, bias, resid, oF, oB, M, N, K, lda, ldb, ldc,
         sAb, sAh, sBb, sBh, sCb, sCh, hdiv, act, ksplit};
    dim3 g((unsigned)((N + 127) / 128), (unsigned)(M / 128), (unsigned)(nb * ksplit));
    gemm_kernel<<<g, 256, 0, stream>>>(p);
  };

  const long WSZ = (long)DMODEL * DMODEL;

  emb_kernel<<<MROWS, 256, 0, stream>>>(tgt, embt, res);
  cvt_kernel<<<(MROWS * DMODEL / 4 + 255) / 256, 256, 0, stream>>>(memb, membb,
                                                                   MROWS * DMODEL / 4);

  for (int l = 0; l < NLAYER; ++l) {
    const float* saw = sa_w + (long)l * 4 * WSZ;
    const float* sab = sa_b + (long)l * 4 * DMODEL;
    const float* caw = ca_w + (long)l * 4 * WSZ;
    const float* cab = ca_b + (long)l * 4 * DMODEL;

    // ======== self-attention ========
    ln_kernel<<<MROWS, 256, 0, stream>>>(res, ln_g + (l * 3 + 0) * DMODEL,
                                         ln_b + (l * 3 + 0) * DMODEL, xb, nullptr);
    cvt_kernel<<<(int)((WSZ + 255) / 256), 256, 0, stream>>>(saw, wA, (int)WSZ);
    gemm(xb, wA, sab, nullptr, nullptr, qkvb, MROWS, 3 * DMODEL, DMODEL,
         DMODEL, DMODEL, 3 * DMODEL, 1, 0, 0, 0, 0, 0, 0, 1, 0, 1);
    attn_kernel<<<dim3(SEQ / QT, BATCH * NHEAD), 256, 0, stream>>>(qkvb, tgt, ctxb, 1);
    gemm(ctxb, wA + 3 * WSZ, sab + 3 * DMODEL, nullptr, res, nullptr, MROWS, DMODEL,
         DMODEL, DMODEL, DMODEL, DMODEL, 1, 0, 0, 0, 0, 0, 0, 1, 0, 4);

    // ======== cross-attention ========
    ln_kernel<<<MROWS, 256, 0, stream>>>(res, ln_g + (l * 3 + 1) * DMODEL,
                                         ln_b + (l * 3 + 1) * DMODEL, xb, nullptr);
    cvt_kernel<<<(int)((WSZ + 255) / 256), 256, 0, stream>>>(caw, wA, (int)WSZ);
    zero_kernel<<<(MROWS * DMODEL / 4 + 255) / 256, 256, 0, stream>>>((float4*)qf,
                                                                      MROWS * DMODEL / 4);
    gemm(xb, wA, cab, nullptr, qf, nullptr, MROWS, DMODEL, DMODEL,
         DMODEL, DMODEL, DMODEL, 1, 0, 0, 0, 0, 0, 0, 1, 0, 4);
    cvt2d_kernel<<<MROWS, 256, 0, stream>>>(qf, qkvb);
    gemm(membb, wA + WSZ, cab + DMODEL, nullptr, nullptr, qkvb + DMODEL, MROWS,
         2 * DMODEL, DMODEL, DMODEL, DMODEL, 3 * DMODEL, 1, 0, 0, 0, 0, 0, 0, 1, 0, 1);
    attn_kernel<<<dim3(SEQ / QT, BATCH * NHEAD), 256, 0, stream>>>(qkvb, srct, ctxb, 0);
    gemm(ctxb, wA + 3 * WSZ, cab + 3 * DMODEL, nullptr, res, nullptr, MROWS, DMODEL,
         DMODEL, DMODEL, DMODEL, DMODEL, 1, 0, 0, 0, 0, 0, 0, 1, 0, 4);

    // ======== FFN ========
    ln_kernel<<<MROWS, 256, 0, stream>>>(res, ln_g + (l * 3 + 2) * DMODEL,
                                         ln_b + (l * 3 + 2) * DMODEL, xb, nullptr);
    cvt_kernel<<<(int)((DFFN * (long)DMODEL / 4 + 255) / 256), 256, 0, stream>>>(
        ff_w1 + (long)l * DFFN * DMODEL, wF1, (int)(DFFN * (long)DMODEL / 4));
    cvt_kernel<<<(int)((DFFN * (long)DMODEL / 4 + 255) / 256), 256, 0, stream>>>(
        ff_w2 + (long)l * DFFN * DMODEL, wF2, (int)(DFFN * (long)DMODEL / 4));
    gemm(xb, wF1, ff_b1 + (long)l * DFFN, nullptr, nullptr, ffh, MROWS, DFFN,
         DMODEL, DMODEL, DMODEL, DFFN, 1, 0, 0, 0, 0, 0, 0, 1, 1, 1);
    gemm(ffh, wF2, ff_b2 + (long)l * DMODEL, nullptr, res, nullptr, MROWS, DMODEL,
         DFFN, DFFN, DFFN, DMODEL, 1, 0, 0, 0, 0, 0, 0, 1, 0, 4);
  }

  ln_kernel<<<MROWS, 256, 0, stream>>>(res, out_g, out_b, nullptr, out);
}

// Round 3
// 2690.213 us; speedup vs baseline: 1.2705x; 1.2031x over previous
//
#include <hip/hip_runtime.h>
#include <math.h>
#include <stdint.h>

typedef __bf16 bf16_t;
typedef __bf16 bf16x8 __attribute__((ext_vector_type(8)));
typedef __bf16 bf16x4 __attribute__((ext_vector_type(4)));
typedef float f32x4 __attribute__((ext_vector_type(4)));

#define NLAYER 6
#define DMODEL 768
#define NHEAD 12
#define DHEAD 64
#define SEQ 512
#define BATCH 8
#define MROWS 4096 /* BATCH*SEQ */
#define DFFN 3072

// ---------- helpers ----------

__device__ inline void async_load16(const void* g, void* lds) {
  const __attribute__((address_space(1))) void* gp =
      (const __attribute__((address_space(1))) void*)(uintptr_t)g;
  __attribute__((address_space(3))) void* lp =
      (__attribute__((address_space(3))) void*)(uint32_t)(uintptr_t)lds;
  __builtin_amdgcn_global_load_lds(gp, lp, 16, 0, 0);
}

__device__ inline float wsum(float v) {
#pragma unroll
  for (int o = 32; o > 0; o >>= 1) v += __shfl_xor(v, o, 64);
  return v;
}

__device__ inline float gelu_f(float x) {
  float u = 0.7978845608028654f * (x + 0.044715f * x * x * x);
  return 0.5f * x * (1.0f + tanhf(u));
}

// ---------- GEMM:  C[m,n] = sum_k A[m,k] * B[n,k]  (B is [N,K] row-major) ----------
// grid: x = M-tiles (fastest -> one XCD per m-tile), y = N-tiles, z = k-split
struct GP {
  const bf16_t* A;
  const bf16_t* B;
  const float* bias;   // [N] or null (ignored when ksplit>1)
  const float* resid;  // f32, ldc layout, or null
  float* outF;         // f32 out (or partial base when ksplit>1)
  bf16_t* outB;        // bf16 out or null
  int M, N, K;
  int lda, ldb, ldc;
  long pstride;  // partial-buffer stride (elements) for ksplit>1
  int act;       // 1 = gelu
  int ksplit;
};

__global__ __launch_bounds__(256) void gemm_kernel(GP p) {
  __shared__ __align__(16) bf16_t As[128 * 32];
  __shared__ __align__(16) bf16_t Bs[128 * 32];
  const int tid = threadIdx.x;
  const int wave = tid >> 6, lane = tid & 63;
  const int wr = wave >> 1, wc = wave & 1;
  const int lrow = lane & 15, kq = lane >> 4;
  const int sr = tid >> 2;
  const int sc = (tid & 3) << 3;
  const int m0 = blockIdx.x * 128;
  const int n0 = blockIdx.y * 128;
  const int zs = (int)blockIdx.z;

  const int kc = p.K / p.ksplit;
  const int kstart = zs * kc;

  f32x4 acc[4][4] = {};

  for (int k0 = kstart; k0 < kstart + kc; k0 += 32) {
#pragma unroll
    for (int r = 0; r < 2; ++r) {
      const bf16_t* gp = p.A + (long)(m0 + r * 64 + sr) * p.lda + (k0 + sc);
      async_load16(gp, &As[(r * 64 + wave * 16) * 32]);
    }
#pragma unroll
    for (int r = 0; r < 2; ++r) {
      const bf16_t* gp = p.B + (long)(n0 + r * 64 + sr) * p.ldb + (k0 + sc);
      async_load16(gp, &Bs[(r * 64 + wave * 16) * 32]);
    }
    __syncthreads();

    bf16x8 af[4], bfr[4];
#pragma unroll
    for (int i = 0; i < 4; ++i)
      af[i] = *(const bf16x8*)&As[(wr * 64 + i * 16 + lrow) * 32 + kq * 8];
#pragma unroll
    for (int j = 0; j < 4; ++j)
      bfr[j] = *(const bf16x8*)&Bs[(wc * 64 + j * 16 + lrow) * 32 + kq * 8];
#pragma unroll
    for (int i = 0; i < 4; ++i)
#pragma unroll
      for (int j = 0; j < 4; ++j)
        acc[i][j] = __builtin_amdgcn_mfma_f32_16x16x32_bf16(af[i], bfr[j], acc[i][j], 0, 0, 0);
    __syncthreads();
  }

  const int crow0 = m0 + wr * 64 + kq * 4;
  const int ccol0 = n0 + wc * 64 + lrow;
  if (p.ksplit > 1) {
    float* po = p.outF + (long)zs * p.pstride;
#pragma unroll
    for (int j = 0; j < 4; ++j) {
      const int col = ccol0 + j * 16;
#pragma unroll
      for (int i = 0; i < 4; ++i)
#pragma unroll
        for (int r = 0; r < 4; ++r)
          po[(long)(crow0 + i * 16 + r) * p.ldc + col] = acc[i][j][r];
    }
  } else {
#pragma unroll
    for (int j = 0; j < 4; ++j) {
      const int col = ccol0 + j * 16;
#pragma unroll
      for (int i = 0; i < 4; ++i) {
#pragma unroll
        for (int r = 0; r < 4; ++r) {
          const int row = crow0 + i * 16 + r;
          const long idx = (long)row * p.ldc + col;
          float y = acc[i][j][r];
          if (p.bias) y += p.bias[col];
          if (p.resid) y += p.resid[idx];
          if (p.act) y = gelu_f(y);
          if (p.outF) p.outF[idx] = y;
          if (p.outB) p.outB[idx] = (bf16_t)y;
        }
      }
    }
  }
}

// ---------- fused flash attention ----------
#define QT 64
#define KT 128
#define VPAD 136

__global__ __launch_bounds__(256) void attn_kernel(const bf16_t* __restrict__ qkv,
                                                   const int* __restrict__ toks,
                                                   bf16_t* __restrict__ ctx, int causal) {
  __shared__ __align__(16) bf16_t Qs[QT * 64];
  __shared__ __align__(16) bf16_t Ks[KT * 64];
  __shared__ __align__(16) bf16_t Vs[64 * VPAD];
  __shared__ __align__(16) bf16_t Ps[QT * VPAD];
  __shared__ int Ts[SEQ];
  const int tid = threadIdx.x;
  const int wave = tid >> 6, lane = tid & 63;
  const int lm = lane & 15, lq = lane >> 4;
  const int q0 = blockIdx.x * QT;
  const int bh = blockIdx.y;
  const int b = bh / NHEAD, h = bh % NHEAD;
  const long rowbase = (long)b * SEQ;
  const int LD = 3 * DMODEL;
  const bf16_t* Qg = qkv + (rowbase + q0) * LD + h * DHEAD;
  const bf16_t* Kg = qkv + rowbase * LD + DMODEL + h * DHEAD;
  const bf16_t* Vg = qkv + rowbase * LD + 2 * DMODEL + h * DHEAD;

  Ts[tid] = toks[b * SEQ + tid];
  Ts[tid + 256] = toks[b * SEQ + tid + 256];

#pragma unroll
  for (int r = 0; r < 2; ++r) {
    const int c = r * 256 + tid;
    const int row = c >> 3, c8 = (c & 7) * 8;
    async_load16(Qg + (long)row * LD + c8, &Qs[c * 8]);
  }
  __syncthreads();

  bf16x8 aQ0 = *(const bf16x8*)&Qs[(wave * 16 + lm) * 64 + lq * 8];
  bf16x8 aQ1 = *(const bf16x8*)&Qs[(wave * 16 + lm) * 64 + 32 + lq * 8];

  float m_i[4], l_i[4];
  f32x4 O[4] = {};
#pragma unroll
  for (int r = 0; r < 4; ++r) { m_i[r] = -3.0e38f; l_i[r] = 0.0f; }

  const int s_end = causal ? (q0 + QT) : SEQ;
  for (int s0 = 0; s0 < s_end; s0 += KT) {
    __syncthreads();
#pragma unroll
    for (int r = 0; r < 4; ++r) {
      const int c = r * 256 + tid;
      const int row = c >> 3, c8 = (c & 7) * 8;
      async_load16(Kg + (long)(s0 + row) * LD + c8, &Ks[c * 8]);
    }
#pragma unroll
    for (int r = 0; r < 4; ++r) {
      const int c = r * 256 + tid;
      const int row = c >> 3, c8 = (c & 7) * 8;
      const bf16x8 vv = *(const bf16x8*)(Vg + (long)(s0 + row) * LD + c8);
#pragma unroll
      for (int j = 0; j < 8; ++j) Vs[(c8 + j) * VPAD + row] = vv[j];
    }
    __syncthreads();

    f32x4 sv[8];
#pragma unroll
    for (int jt = 0; jt < 8; ++jt) {
      const bf16x8 b0 = *(const bf16x8*)&Ks[(jt * 16 + lm) * 64 + lq * 8];
      const bf16x8 b1 = *(const bf16x8*)&Ks[(jt * 16 + lm) * 64 + 32 + lq * 8];
      f32x4 a = {};
      a = __builtin_amdgcn_mfma_f32_16x16x32_bf16(aQ0, b0, a, 0, 0, 0);
      a = __builtin_amdgcn_mfma_f32_16x16x32_bf16(aQ1, b1, a, 0, 0, 0);
      sv[jt] = a;
    }

#pragma unroll
    for (int r = 0; r < 4; ++r) {
      const int qa = q0 + wave * 16 + lq * 4 + r;
      float sr[8];
      float mx = -3.0e38f;
#pragma unroll
      for (int jt = 0; jt < 8; ++jt) {
        const int k = s0 + jt * 16 + lm;
        const float x = sv[jt][r] * 0.125f;
        const bool msk = (Ts[k] == 0) || (causal && (k > qa));
        sr[jt] = msk ? -1.0e18f : x;
        mx = fmaxf(mx, sr[jt]);
      }
#pragma unroll
      for (int o = 1; o < 16; o <<= 1) mx = fmaxf(mx, __shfl_xor(mx, o, 64));
      const float mn = fmaxf(m_i[r], mx);
      const float alpha = __expf(m_i[r] - mn);
      float sum = 0.0f;
#pragma unroll
      for (int jt = 0; jt < 8; ++jt) {
        const float pv = __expf(sr[jt] - mn);
        sr[jt] = pv;
        sum += pv;
      }
#pragma unroll
      for (int o = 1; o < 16; o <<= 1) sum += __shfl_xor(sum, o, 64);
      l_i[r] = l_i[r] * alpha + sum;
      m_i[r] = mn;
#pragma unroll
      for (int jn = 0; jn < 4; ++jn) O[jn][r] *= alpha;
#pragma unroll
      for (int jt = 0; jt < 8; ++jt)
        Ps[(wave * 16 + lq * 4 + r) * VPAD + jt * 16 + lm] = (bf16_t)sr[jt];
    }

#pragma unroll
    for (int kt = 0; kt < 4; ++kt) {
      const bf16x8 aP = *(const bf16x8*)&Ps[(wave * 16 + lm) * VPAD + kt * 32 + lq * 8];
#pragma unroll
      for (int jn = 0; jn < 4; ++jn) {
        const bf16x8 bV = *(const bf16x8*)&Vs[(jn * 16 + lm) * VPAD + kt * 32 + lq * 8];
        O[jn] = __builtin_amdgcn_mfma_f32_16x16x32_bf16(aP, bV, O[jn], 0, 0, 0);
      }
    }
  }

#pragma unroll
  for (int r = 0; r < 4; ++r) {
    const int q = q0 + wave * 16 + lq * 4 + r;
    const float inv = 1.0f / l_i[r];
#pragma unroll
    for (int jn = 0; jn < 4; ++jn) {
      const int d = jn * 16 + lm;
      ctx[(rowbase + q) * DMODEL + h * DHEAD + d] = (bf16_t)(O[jn][r] * inv);
    }
  }
}

// ---------- LayerNorm (row = 768) ----------
__global__ __launch_bounds__(256) void ln_kernel(const float* __restrict__ X,
                                                 const float* __restrict__ g,
                                                 const float* __restrict__ b,
                                                 bf16_t* __restrict__ outB,
                                                 float* __restrict__ outF) {
  const int row = blockIdx.x, tid = threadIdx.x;
  const float* xr = X + (long)row * DMODEL;
  const float v0 = xr[tid], v1 = xr[tid + 256], v2 = xr[tid + 512];
  __shared__ float r1[4], r2[4];
  const int wv = tid >> 6, ln = tid & 63;
  float s = wsum(v0 + v1 + v2);
  if (ln == 0) r1[wv] = s;
  __syncthreads();
  const float mean = (r1[0] + r1[1] + r1[2] + r1[3]) * (1.0f / DMODEL);
  const float d0 = v0 - mean, d1 = v1 - mean, d2 = v2 - mean;
  float q = wsum(d0 * d0 + d1 * d1 + d2 * d2);
  if (ln == 0) r2[wv] = q;
  __syncthreads();
  const float var = (r2[0] + r2[1] + r2[2] + r2[3]) * (1.0f / DMODEL);
  const float rs = rsqrtf(var + 1e-6f);
  const float y0 = d0 * rs * g[tid] + b[tid];
  const float y1 = d1 * rs * g[tid + 256] + b[tid + 256];
  const float y2 = d2 * rs * g[tid + 512] + b[tid + 512];
  const long base = (long)row * DMODEL;
  if (outB) {
    outB[base + tid] = (bf16_t)y0;
    outB[base + tid + 256] = (bf16_t)y1;
    outB[base + tid + 512] = (bf16_t)y2;
  }
  if (outF) {
    outF[base + tid] = y0;
    outF[base + tid + 256] = y1;
    outF[base + tid + 512] = y2;
  }
}

// ---------- reduce split-K partials + bias + residual, then LayerNorm ----------
__global__ __launch_bounds__(256) void reduce_ln_kernel(
    const float* __restrict__ parts, long pstr, int np,
    const float* __restrict__ bias, float* __restrict__ res,
    const float* __restrict__ g, const float* __restrict__ b,
    bf16_t* __restrict__ outB, float* __restrict__ outF) {
  const int row = blockIdx.x, tid = threadIdx.x;
  const long base = (long)row * DMODEL;
  float v0, v1, v2;
  {
    float t0 = res[base + tid] + bias[tid];
    float t1 = res[base + tid + 256] + bias[tid + 256];
    float t2 = res[base + tid + 512] + bias[tid + 512];
    for (int p = 0; p < np; ++p) {
      const float* pp = parts + p * pstr + base;
      t0 += pp[tid];
      t1 += pp[tid + 256];
      t2 += pp[tid + 512];
    }
    v0 = t0; v1 = t1; v2 = t2;
    res[base + tid] = t0;
    res[base + tid + 256] = t1;
    res[base + tid + 512] = t2;
  }
  __shared__ float r1[4], r2[4];
  const int wv = tid >> 6, ln = tid & 63;
  float s = wsum(v0 + v1 + v2);
  if (ln == 0) r1[wv] = s;
  __syncthreads();
  const float mean = (r1[0] + r1[1] + r1[2] + r1[3]) * (1.0f / DMODEL);
  const float d0 = v0 - mean, d1 = v1 - mean, d2 = v2 - mean;
  float q = wsum(d0 * d0 + d1 * d1 + d2 * d2);
  if (ln == 0) r2[wv] = q;
  __syncthreads();
  const float var = (r2[0] + r2[1] + r2[2] + r2[3]) * (1.0f / DMODEL);
  const float rs = rsqrtf(var + 1e-6f);
  const float y0 = d0 * rs * g[tid] + b[tid];
  const float y1 = d1 * rs * g[tid + 256] + b[tid + 256];
  const float y2 = d2 * rs * g[tid + 512] + b[tid + 512];
  if (outB) {
    outB[base + tid] = (bf16_t)y0;
    outB[base + tid + 256] = (bf16_t)y1;
    outB[base + tid + 512] = (bf16_t)y2;
  }
  if (outF) {
    outF[base + tid] = y0;
    outF[base + tid + 256] = y1;
    outF[base + tid + 512] = y2;
  }
}

// ---------- reduce split-K partials + bias -> strided bf16 (CA-q into qkv) ----------
__global__ __launch_bounds__(256) void reduce_cvtq_kernel(
    const float* __restrict__ parts, long pstr, int np,
    const float* __restrict__ bias, bf16_t* __restrict__ o) {
  const int row = blockIdx.x, tid = threadIdx.x;
  const long base = (long)row * DMODEL;
  const long ob = (long)row * 3 * DMODEL;
#pragma unroll
  for (int c = 0; c < 3; ++c) {
    const int col = tid + c * 256;
    float t = bias[col];
    for (int p = 0; p < np; ++p) t += parts[p * pstr + base + col];
    o[ob + col] = (bf16_t)t;
  }
}

// ---------- embedding * sqrt(D) + sinusoidal PE ----------
__global__ __launch_bounds__(256) void emb_kernel(const int* __restrict__ tgt,
                                                  const float* __restrict__ tab,
                                                  float* __restrict__ res) {
  const int row = blockIdx.x;
  const int t = row & (SEQ - 1);
  const long tok = tgt[row];
  const float* er = tab + tok * DMODEL;
  float* orow = res + (long)row * DMODEL;
  const float c1 = -9.210340371976184f / 768.0f;
  for (int c = threadIdx.x; c < DMODEL; c += 256) {
    const float e = er[c] * 27.712812921102035f;
    const float div = expf((float)(c & ~1) * c1);
    const float ang = (float)t * div;
    const float pe = (c & 1) ? cosf(ang) : sinf(ang);
    orow[c] = e + pe;
  }
}

// ---------- f32 -> bf16 convert (n4 = n/4) ----------
__global__ __launch_bounds__(256) void cvt_kernel(const float* __restrict__ in,
                                                  bf16_t* __restrict__ o, int n4) {
  const int i = blockIdx.x * 256 + threadIdx.x;
  if (i < n4) {
    const float4 v = ((const float4*)in)[i];
    bf16x4 r = {(bf16_t)v.x, (bf16_t)v.y, (bf16_t)v.z, (bf16_t)v.w};
    ((bf16x4*)o)[i] = r;
  }
}

// ---------- host ----------
extern "C" void kernel_launch(void* const* d_in, const int* in_sizes, int n_in,
                              void* d_out, int out_size, void* d_ws, size_t ws_size,
                              hipStream_t stream) {
  (void)in_sizes; (void)n_in; (void)out_size; (void)ws_size;
  const int* tgt = (const int*)d_in[0];
  const int* srct = (const int*)d_in[1];
  const float* memb = (const float*)d_in[2];
  const float* embt = (const float*)d_in[3];
  const float* sa_w = (const float*)d_in[4];
  const float* sa_b = (const float*)d_in[5];
  const float* ca_w = (const float*)d_in[6];
  const float* ca_b = (const float*)d_in[7];
  const float* ln_g = (const float*)d_in[8];
  const float* ln_b = (const float*)d_in[9];
  const float* ff_w1 = (const float*)d_in[10];
  const float* ff_b1 = (const float*)d_in[11];
  const float* ff_w2 = (const float*)d_in[12];
  const float* ff_b2 = (const float*)d_in[13];
  const float* out_g = (const float*)d_in[14];
  const float* out_b = (const float*)d_in[15];
  float* out = (float*)d_out;

  char* wsb = (char*)d_ws;
  size_t off = 0;
  auto alloc = [&](size_t bytes) -> void* {
    void* pp = wsb + off;
    off = (off + bytes + 255) & ~(size_t)255;
    return pp;
  };
  float* res = (float*)alloc((size_t)MROWS * DMODEL * 4);
  float* parts = (float*)alloc((size_t)2 * MROWS * DMODEL * 4);  // split-K partials
  bf16_t* xb = (bf16_t*)alloc((size_t)MROWS * DMODEL * 2);
  bf16_t* qkvb = (bf16_t*)alloc((size_t)MROWS * 3 * DMODEL * 2);
  bf16_t* ctxb = (bf16_t*)alloc((size_t)MROWS * DMODEL * 2);
  bf16_t* membb = (bf16_t*)alloc((size_t)MROWS * DMODEL * 2);
  bf16_t* ffh = (bf16_t*)alloc((size_t)MROWS * DFFN * 2);
  bf16_t* wA = (bf16_t*)alloc((size_t)4 * DMODEL * DMODEL * 2);
  bf16_t* wF1 = (bf16_t*)alloc((size_t)DFFN * DMODEL * 2);
  bf16_t* wF2 = (bf16_t*)alloc((size_t)DFFN * DMODEL * 2);

  const long PSTR = (long)MROWS * DMODEL;

  auto gemm = [&](const bf16_t* A, const bf16_t* Bm, const float* bias,
                  const float* resid, float* oF, bf16_t* oB, int M, int N, int K,
                  int lda, int ldb, int ldc, int act, int ksplit) {
    GP p{A, Bm, bias, resid, oF, oB, M, N, K, lda, ldb, ldc, PSTR, act, ksplit};
    dim3 g((unsigned)(M / 128), (unsigned)(N / 128), (unsigned)ksplit);
    gemm_kernel<<<g, 256, 0, stream>>>(p);
  };

  const long WSZ = (long)DMODEL * DMODEL;

  emb_kernel<<<MROWS, 256, 0, stream>>>(tgt, embt, res);
  cvt_kernel<<<(MROWS * DMODEL / 4 + 255) / 256, 256, 0, stream>>>(memb, membb,
                                                                   MROWS * DMODEL / 4);
  ln_kernel<<<MROWS, 256, 0, stream>>>(res, ln_g, ln_b, xb, nullptr);

  for (int l = 0; l < NLAYER; ++l) {
    const float* saw = sa_w + (long)l * 4 * WSZ;
    const float* sab = sa_b + (long)l * 4 * DMODEL;
    const float* caw = ca_w + (long)l * 4 * WSZ;
    const float* cab = ca_b + (long)l * 4 * DMODEL;

    // ======== self-attention ========   (xb = ln1(res) already available)
    cvt_kernel<<<(int)((WSZ + 255) / 256), 256, 0, stream>>>(saw, wA, (int)WSZ);
    gemm(xb, wA, sab, nullptr, nullptr, qkvb, MROWS, 3 * DMODEL, DMODEL,
         DMODEL, DMODEL, 3 * DMODEL, 0, 1);
    attn_kernel<<<dim3(SEQ / QT, BATCH * NHEAD), 256, 0, stream>>>(qkvb, tgt, ctxb, 1);
    gemm(ctxb, wA + 3 * WSZ, nullptr, nullptr, parts, nullptr, MROWS, DMODEL, DMODEL,
         DMODEL, DMODEL, DMODEL, 0, 2);
    reduce_ln_kernel<<<MROWS, 256, 0, stream>>>(parts, PSTR, 2, sab + 3 * DMODEL, res,
                                                ln_g + (l * 3 + 1) * DMODEL,
                                                ln_b + (l * 3 + 1) * DMODEL, xb, nullptr);

    // ======== cross-attention ========  (xb = ln2)
    cvt_kernel<<<(int)((WSZ + 255) / 256), 256, 0, stream>>>(caw, wA, (int)WSZ);
    gemm(xb, wA, nullptr, nullptr, parts, nullptr, MROWS, DMODEL, DMODEL,
         DMODEL, DMODEL, DMODEL, 0, 2);
    reduce_cvtq_kernel<<<MROWS, 256, 0, stream>>>(parts, PSTR, 2, cab, qkvb);
    gemm(membb, wA + WSZ, cab + DMODEL, nullptr, nullptr, qkvb + DMODEL, MROWS,
         2 * DMODEL, DMODEL, DMODEL, DMODEL, 3 * DMODEL, 0, 1);
    attn_kernel<<<dim3(SEQ / QT, BATCH * NHEAD), 256, 0, stream>>>(qkvb, srct, ctxb, 0);
    gemm(ctxb, wA + 3 * WSZ, nullptr, nullptr, parts, nullptr, MROWS, DMODEL, DMODEL,
         DMODEL, DMODEL, DMODEL, 0, 2);
    reduce_ln_kernel<<<MROWS, 256, 0, stream>>>(parts, PSTR, 2, cab + 3 * DMODEL, res,
                                                ln_g + (l * 3 + 2) * DMODEL,
                                                ln_b + (l * 3 + 2) * DMODEL, xb, nullptr);

    // ======== FFN ========  (xb = ln3)
    cvt_kernel<<<(int)((DFFN * (long)DMODEL / 4 + 255) / 256), 256, 0, stream>>>(
        ff_w1 + (long)l * DFFN * DMODEL, wF1, (int)(DFFN * (long)DMODEL / 4));
    cvt_kernel<<<(int)((DFFN * (long)DMODEL / 4 + 255) / 256), 256, 0, stream>>>(
        ff_w2 + (long)l * DFFN * DMODEL, wF2, (int)(DFFN * (long)DMODEL / 4));
    gemm(xb, wF1, ff_b1 + (long)l * DFFN, nullptr, nullptr, ffh, MROWS, DFFN,
         DMODEL, DMODEL, DMODEL, DFFN, 1, 1);
    gemm(ffh, wF2, nullptr, nullptr, parts, nullptr, MROWS, DMODEL, DFFN,
         DFFN, DFFN, DMODEL, 0, 2);
    if (l < NLAYER - 1) {
      reduce_ln_kernel<<<MROWS, 256, 0, stream>>>(parts, PSTR, 2, ff_b2 + (long)l * DMODEL,
                                                  res, ln_g + ((l + 1) * 3) * DMODEL,
                                                  ln_b + ((l + 1) * 3) * DMODEL, xb, nullptr);
    } else {
      reduce_ln_kernel<<<MROWS, 256, 0, stream>>>(parts, PSTR, 2, ff_b2 + (long)l * DMODEL,
                                                  res, out_g, out_b, nullptr, out);
    }
  }
}

// Round 4
// 2355.767 us; speedup vs baseline: 1.4509x; 1.1420x over previous
//
#include <hip/hip_runtime.h>
#include <math.h>
#include <stdint.h>

typedef __bf16 bf16_t;
typedef __bf16 bf16x8 __attribute__((ext_vector_type(8)));
typedef __bf16 bf16x4 __attribute__((ext_vector_type(4)));
typedef float f32x4 __attribute__((ext_vector_type(4)));

#define NLAYER 6
#define DMODEL 768
#define NHEAD 12
#define DHEAD 64
#define SEQ 512
#define BATCH 8
#define MROWS 4096 /* BATCH*SEQ */
#define DFFN 3072

// ---------- helpers ----------

__device__ inline void async_load16(const void* g, void* lds) {
  const __attribute__((address_space(1))) void* gp =
      (const __attribute__((address_space(1))) void*)(uintptr_t)g;
  __attribute__((address_space(3))) void* lp =
      (__attribute__((address_space(3))) void*)(uint32_t)(uintptr_t)lds;
  __builtin_amdgcn_global_load_lds(gp, lp, 16, 0, 0);
}

__device__ inline float wsum(float v) {
#pragma unroll
  for (int o = 32; o > 0; o >>= 1) v += __shfl_xor(v, o, 64);
  return v;
}

__device__ inline float gelu_f(float x) {
  float u = 0.7978845608028654f * (x + 0.044715f * x * x * x);
  return 0.5f * x * (1.0f + tanhf(u));
}

// ---------- GEMM:  C[m,n] = sum_k A[m,k] * B[n,k]  (B is [N,K] row-major) ----------
// grid: x = M-tiles (fastest -> one XCD per m-tile), y = N-tiles, z = k-split
// K-loop: double-buffered LDS, raw s_barrier + vmcnt(4) (m139 pattern) so the
// next tile's global_load_lds stays in flight across the barrier.
struct GP {
  const bf16_t* A;
  const bf16_t* B;
  const float* bias;   // [N] or null (ignored when ksplit>1)
  const float* resid;  // f32, ldc layout, or null
  float* outF;         // f32 out (or partial base when ksplit>1)
  bf16_t* outB;        // bf16 out or null
  int M, N, K;
  int lda, ldb, ldc;
  long pstride;  // partial-buffer stride (elements) for ksplit>1
  int act;       // 1 = gelu
  int ksplit;
};

__global__ __launch_bounds__(256) void gemm_kernel(GP p) {
  __shared__ __align__(16) bf16_t As[2][128 * 32];
  __shared__ __align__(16) bf16_t Bs[2][128 * 32];
  const int tid = threadIdx.x;
  const int wave = tid >> 6, lane = tid & 63;
  const int wr = wave >> 1, wc = wave & 1;
  const int lrow = lane & 15, kq = lane >> 4;
  const int sr = tid >> 2;
  const int sc = (tid & 3) << 3;
  const int m0 = blockIdx.x * 128;
  const int n0 = blockIdx.y * 128;
  const int zs = (int)blockIdx.z;

  const int kc = p.K / p.ksplit;
  const int kstart = zs * kc;
  const int kend = kstart + kc;

  auto stage = [&](int k0, int buf) {
#pragma unroll
    for (int r = 0; r < 2; ++r)
      async_load16(p.A + (long)(m0 + r * 64 + sr) * p.lda + (k0 + sc),
                   &As[buf][(r * 64 + wave * 16) * 32]);
#pragma unroll
    for (int r = 0; r < 2; ++r)
      async_load16(p.B + (long)(n0 + r * 64 + sr) * p.ldb + (k0 + sc),
                   &Bs[buf][(r * 64 + wave * 16) * 32]);
  };

  f32x4 acc[4][4] = {};
  stage(kstart, 0);
  int cur = 0;

  for (int k0 = kstart; k0 < kend; k0 += 32) {
    const bool hn = (k0 + 32) < kend;
    if (hn) {
      stage(k0 + 32, cur ^ 1);
      __builtin_amdgcn_s_waitcnt(0xF74);  // vmcnt(4): cur buf's 4 loads done
    } else {
      __builtin_amdgcn_s_waitcnt(0xF70);  // vmcnt(0)
    }
    __builtin_amdgcn_s_barrier();

    bf16x8 af[4], bfr[4];
#pragma unroll
    for (int i = 0; i < 4; ++i)
      af[i] = *(const bf16x8*)&As[cur][(wr * 64 + i * 16 + lrow) * 32 + kq * 8];
#pragma unroll
    for (int j = 0; j < 4; ++j)
      bfr[j] = *(const bf16x8*)&Bs[cur][(wc * 64 + j * 16 + lrow) * 32 + kq * 8];
#pragma unroll
    for (int i = 0; i < 4; ++i)
#pragma unroll
      for (int j = 0; j < 4; ++j)
        acc[i][j] = __builtin_amdgcn_mfma_f32_16x16x32_bf16(af[i], bfr[j], acc[i][j], 0, 0, 0);

    __builtin_amdgcn_s_barrier();  // all waves done reading cur before overwrite
    cur ^= 1;
  }

  const int crow0 = m0 + wr * 64 + kq * 4;
  const int ccol0 = n0 + wc * 64 + lrow;
  if (p.ksplit > 1) {
    float* po = p.outF + (long)zs * p.pstride;
#pragma unroll
    for (int j = 0; j < 4; ++j) {
      const int col = ccol0 + j * 16;
#pragma unroll
      for (int i = 0; i < 4; ++i)
#pragma unroll
        for (int r = 0; r < 4; ++r)
          po[(long)(crow0 + i * 16 + r) * p.ldc + col] = acc[i][j][r];
    }
  } else {
#pragma unroll
    for (int j = 0; j < 4; ++j) {
      const int col = ccol0 + j * 16;
#pragma unroll
      for (int i = 0; i < 4; ++i) {
#pragma unroll
        for (int r = 0; r < 4; ++r) {
          const int row = crow0 + i * 16 + r;
          const long idx = (long)row * p.ldc + col;
          float y = acc[i][j][r];
          if (p.bias) y += p.bias[col];
          if (p.resid) y += p.resid[idx];
          if (p.act) y = gelu_f(y);
          if (p.outF) p.outF[idx] = y;
          if (p.outB) p.outB[idx] = (bf16_t)y;
        }
      }
    }
  }
}

// ---------- fused flash attention ----------
#define QT 64
#define KT 128
#define VPAD 136

__global__ __launch_bounds__(256) void attn_kernel(const bf16_t* __restrict__ qkv,
                                                   const int* __restrict__ toks,
                                                   bf16_t* __restrict__ ctx, int causal) {
  __shared__ __align__(16) bf16_t Qs[QT * 64];
  __shared__ __align__(16) bf16_t Ks[KT * 64];
  __shared__ __align__(16) bf16_t Vs[64 * VPAD];
  __shared__ __align__(16) bf16_t Ps[QT * VPAD];
  __shared__ int Ts[SEQ];
  const int tid = threadIdx.x;
  const int wave = tid >> 6, lane = tid & 63;
  const int lm = lane & 15, lq = lane >> 4;
  const int q0 = blockIdx.x * QT;
  const int bh = blockIdx.y;
  const int b = bh / NHEAD, h = bh % NHEAD;
  const long rowbase = (long)b * SEQ;
  const int LD = 3 * DMODEL;
  const bf16_t* Qg = qkv + (rowbase + q0) * LD + h * DHEAD;
  const bf16_t* Kg = qkv + rowbase * LD + DMODEL + h * DHEAD;
  const bf16_t* Vg = qkv + rowbase * LD + 2 * DMODEL + h * DHEAD;

  Ts[tid] = toks[b * SEQ + tid];
  Ts[tid + 256] = toks[b * SEQ + tid + 256];

#pragma unroll
  for (int r = 0; r < 2; ++r) {
    const int c = r * 256 + tid;
    const int row = c >> 3, c8 = (c & 7) * 8;
    async_load16(Qg + (long)row * LD + c8, &Qs[c * 8]);
  }
  __syncthreads();

  bf16x8 aQ0 = *(const bf16x8*)&Qs[(wave * 16 + lm) * 64 + lq * 8];
  bf16x8 aQ1 = *(const bf16x8*)&Qs[(wave * 16 + lm) * 64 + 32 + lq * 8];

  float m_i[4], l_i[4];
  f32x4 O[4] = {};
#pragma unroll
  for (int r = 0; r < 4; ++r) { m_i[r] = -3.0e38f; l_i[r] = 0.0f; }

  const int s_end = causal ? (q0 + QT) : SEQ;
  for (int s0 = 0; s0 < s_end; s0 += KT) {
    __syncthreads();
#pragma unroll
    for (int r = 0; r < 4; ++r) {
      const int c = r * 256 + tid;
      const int row = c >> 3, c8 = (c & 7) * 8;
      async_load16(Kg + (long)(s0 + row) * LD + c8, &Ks[c * 8]);
    }
#pragma unroll
    for (int r = 0; r < 4; ++r) {
      const int c = r * 256 + tid;
      const int row = c >> 3, c8 = (c & 7) * 8;
      const bf16x8 vv = *(const bf16x8*)(Vg + (long)(s0 + row) * LD + c8);
#pragma unroll
      for (int j = 0; j < 8; ++j) Vs[(c8 + j) * VPAD + row] = vv[j];
    }
    __syncthreads();

    f32x4 sv[8];
#pragma unroll
    for (int jt = 0; jt < 8; ++jt) {
      const bf16x8 b0 = *(const bf16x8*)&Ks[(jt * 16 + lm) * 64 + lq * 8];
      const bf16x8 b1 = *(const bf16x8*)&Ks[(jt * 16 + lm) * 64 + 32 + lq * 8];
      f32x4 a = {};
      a = __builtin_amdgcn_mfma_f32_16x16x32_bf16(aQ0, b0, a, 0, 0, 0);
      a = __builtin_amdgcn_mfma_f32_16x16x32_bf16(aQ1, b1, a, 0, 0, 0);
      sv[jt] = a;
    }

#pragma unroll
    for (int r = 0; r < 4; ++r) {
      const int qa = q0 + wave * 16 + lq * 4 + r;
      float sr[8];
      float mx = -3.0e38f;
#pragma unroll
      for (int jt = 0; jt < 8; ++jt) {
        const int k = s0 + jt * 16 + lm;
        const float x = sv[jt][r] * 0.125f;
        const bool msk = (Ts[k] == 0) || (causal && (k > qa));
        sr[jt] = msk ? -1.0e18f : x;
        mx = fmaxf(mx, sr[jt]);
      }
#pragma unroll
      for (int o = 1; o < 16; o <<= 1) mx = fmaxf(mx, __shfl_xor(mx, o, 64));
      const float mn = fmaxf(m_i[r], mx);
      const float alpha = __expf(m_i[r] - mn);
      float sum = 0.0f;
#pragma unroll
      for (int jt = 0; jt < 8; ++jt) {
        const float pv = __expf(sr[jt] - mn);
        sr[jt] = pv;
        sum += pv;
      }
#pragma unroll
      for (int o = 1; o < 16; o <<= 1) sum += __shfl_xor(sum, o, 64);
      l_i[r] = l_i[r] * alpha + sum;
      m_i[r] = mn;
#pragma unroll
      for (int jn = 0; jn < 4; ++jn) O[jn][r] *= alpha;
#pragma unroll
      for (int jt = 0; jt < 8; ++jt)
        Ps[(wave * 16 + lq * 4 + r) * VPAD + jt * 16 + lm] = (bf16_t)sr[jt];
    }

#pragma unroll
    for (int kt = 0; kt < 4; ++kt) {
      const bf16x8 aP = *(const bf16x8*)&Ps[(wave * 16 + lm) * VPAD + kt * 32 + lq * 8];
#pragma unroll
      for (int jn = 0; jn < 4; ++jn) {
        const bf16x8 bV = *(const bf16x8*)&Vs[(jn * 16 + lm) * VPAD + kt * 32 + lq * 8];
        O[jn] = __builtin_amdgcn_mfma_f32_16x16x32_bf16(aP, bV, O[jn], 0, 0, 0);
      }
    }
  }

#pragma unroll
  for (int r = 0; r < 4; ++r) {
    const int q = q0 + wave * 16 + lq * 4 + r;
    const float inv = 1.0f / l_i[r];
#pragma unroll
    for (int jn = 0; jn < 4; ++jn) {
      const int d = jn * 16 + lm;
      ctx[(rowbase + q) * DMODEL + h * DHEAD + d] = (bf16_t)(O[jn][r] * inv);
    }
  }
}

// ---------- LayerNorm (row = 768) ----------
__global__ __launch_bounds__(256) void ln_kernel(const float* __restrict__ X,
                                                 const float* __restrict__ g,
                                                 const float* __restrict__ b,
                                                 bf16_t* __restrict__ outB,
                                                 float* __restrict__ outF) {
  const int row = blockIdx.x, tid = threadIdx.x;
  const float* xr = X + (long)row * DMODEL;
  const float v0 = xr[tid], v1 = xr[tid + 256], v2 = xr[tid + 512];
  __shared__ float r1[4], r2[4];
  const int wv = tid >> 6, ln = tid & 63;
  float s = wsum(v0 + v1 + v2);
  if (ln == 0) r1[wv] = s;
  __syncthreads();
  const float mean = (r1[0] + r1[1] + r1[2] + r1[3]) * (1.0f / DMODEL);
  const float d0 = v0 - mean, d1 = v1 - mean, d2 = v2 - mean;
  float q = wsum(d0 * d0 + d1 * d1 + d2 * d2);
  if (ln == 0) r2[wv] = q;
  __syncthreads();
  const float var = (r2[0] + r2[1] + r2[2] + r2[3]) * (1.0f / DMODEL);
  const float rs = rsqrtf(var + 1e-6f);
  const float y0 = d0 * rs * g[tid] + b[tid];
  const float y1 = d1 * rs * g[tid + 256] + b[tid + 256];
  const float y2 = d2 * rs * g[tid + 512] + b[tid + 512];
  const long base = (long)row * DMODEL;
  if (outB) {
    outB[base + tid] = (bf16_t)y0;
    outB[base + tid + 256] = (bf16_t)y1;
    outB[base + tid + 512] = (bf16_t)y2;
  }
  if (outF) {
    outF[base + tid] = y0;
    outF[base + tid + 256] = y1;
    outF[base + tid + 512] = y2;
  }
}

// ---------- reduce split-K partials + bias + residual, then LayerNorm ----------
__global__ __launch_bounds__(256) void reduce_ln_kernel(
    const float* __restrict__ parts, long pstr, int np,
    const float* __restrict__ bias, float* __restrict__ res,
    const float* __restrict__ g, const float* __restrict__ b,
    bf16_t* __restrict__ outB, float* __restrict__ outF) {
  const int row = blockIdx.x, tid = threadIdx.x;
  const long base = (long)row * DMODEL;
  float v0, v1, v2;
  {
    float t0 = res[base + tid] + bias[tid];
    float t1 = res[base + tid + 256] + bias[tid + 256];
    float t2 = res[base + tid + 512] + bias[tid + 512];
    for (int p = 0; p < np; ++p) {
      const float* pp = parts + p * pstr + base;
      t0 += pp[tid];
      t1 += pp[tid + 256];
      t2 += pp[tid + 512];
    }
    v0 = t0; v1 = t1; v2 = t2;
    res[base + tid] = t0;
    res[base + tid + 256] = t1;
    res[base + tid + 512] = t2;
  }
  __shared__ float r1[4], r2[4];
  const int wv = tid >> 6, ln = tid & 63;
  float s = wsum(v0 + v1 + v2);
  if (ln == 0) r1[wv] = s;
  __syncthreads();
  const float mean = (r1[0] + r1[1] + r1[2] + r1[3]) * (1.0f / DMODEL);
  const float d0 = v0 - mean, d1 = v1 - mean, d2 = v2 - mean;
  float q = wsum(d0 * d0 + d1 * d1 + d2 * d2);
  if (ln == 0) r2[wv] = q;
  __syncthreads();
  const float var = (r2[0] + r2[1] + r2[2] + r2[3]) * (1.0f / DMODEL);
  const float rs = rsqrtf(var + 1e-6f);
  const float y0 = d0 * rs * g[tid] + b[tid];
  const float y1 = d1 * rs * g[tid + 256] + b[tid + 256];
  const float y2 = d2 * rs * g[tid + 512] + b[tid + 512];
  if (outB) {
    outB[base + tid] = (bf16_t)y0;
    outB[base + tid + 256] = (bf16_t)y1;
    outB[base + tid + 512] = (bf16_t)y2;
  }
  if (outF) {
    outF[base + tid] = y0;
    outF[base + tid + 256] = y1;
    outF[base + tid + 512] = y2;
  }
}

// ---------- reduce split-K partials + bias -> strided bf16 (CA-q into qkv) ----------
__global__ __launch_bounds__(256) void reduce_cvtq_kernel(
    const float* __restrict__ parts, long pstr, int np,
    const float* __restrict__ bias, bf16_t* __restrict__ o) {
  const int row = blockIdx.x, tid = threadIdx.x;
  const long base = (long)row * DMODEL;
  const long ob = (long)row * 3 * DMODEL;
#pragma unroll
  for (int c = 0; c < 3; ++c) {
    const int col = tid + c * 256;
    float t = bias[col];
    for (int p = 0; p < np; ++p) t += parts[p * pstr + base + col];
    o[ob + col] = (bf16_t)t;
  }
}

// ---------- embedding * sqrt(D) + sinusoidal PE ----------
__global__ __launch_bounds__(256) void emb_kernel(const int* __restrict__ tgt,
                                                  const float* __restrict__ tab,
                                                  float* __restrict__ res) {
  const int row = blockIdx.x;
  const int t = row & (SEQ - 1);
  const long tok = tgt[row];
  const float* er = tab + tok * DMODEL;
  float* orow = res + (long)row * DMODEL;
  const float c1 = -9.210340371976184f / 768.0f;
  for (int c = threadIdx.x; c < DMODEL; c += 256) {
    const float e = er[c] * 27.712812921102035f;
    const float div = expf((float)(c & ~1) * c1);
    const float ang = (float)t * div;
    const float pe = (c & 1) ? cosf(ang) : sinf(ang);
    orow[c] = e + pe;
  }
}

// ---------- f32 -> bf16 convert (n4 = n/4) ----------
__global__ __launch_bounds__(256) void cvt_kernel(const float* __restrict__ in,
                                                  bf16_t* __restrict__ o, int n4) {
  const int i = blockIdx.x * 256 + threadIdx.x;
  if (i < n4) {
    const float4 v = ((const float4*)in)[i];
    bf16x4 r = {(bf16_t)v.x, (bf16_t)v.y, (bf16_t)v.z, (bf16_t)v.w};
    ((bf16x4*)o)[i] = r;
  }
}

// ---------- host ----------
extern "C" void kernel_launch(void* const* d_in, const int* in_sizes, int n_in,
                              void* d_out, int out_size, void* d_ws, size_t ws_size,
                              hipStream_t stream) {
  (void)in_sizes; (void)n_in; (void)out_size; (void)ws_size;
  const int* tgt = (const int*)d_in[0];
  const int* srct = (const int*)d_in[1];
  const float* memb = (const float*)d_in[2];
  const float* embt = (const float*)d_in[3];
  const float* sa_w = (const float*)d_in[4];
  const float* sa_b = (const float*)d_in[5];
  const float* ca_w = (const float*)d_in[6];
  const float* ca_b = (const float*)d_in[7];
  const float* ln_g = (const float*)d_in[8];
  const float* ln_b = (const float*)d_in[9];
  const float* ff_w1 = (const float*)d_in[10];
  const float* ff_b1 = (const float*)d_in[11];
  const float* ff_w2 = (const float*)d_in[12];
  const float* ff_b2 = (const float*)d_in[13];
  const float* out_g = (const float*)d_in[14];
  const float* out_b = (const float*)d_in[15];
  float* out = (float*)d_out;

  char* wsb = (char*)d_ws;
  size_t off = 0;
  auto alloc = [&](size_t bytes) -> void* {
    void* pp = wsb + off;
    off = (off + bytes + 255) & ~(size_t)255;
    return pp;
  };
  float* res = (float*)alloc((size_t)MROWS * DMODEL * 4);
  float* parts = (float*)alloc((size_t)2 * MROWS * DMODEL * 4);  // split-K partials
  bf16_t* xb = (bf16_t*)alloc((size_t)MROWS * DMODEL * 2);
  bf16_t* qkvb = (bf16_t*)alloc((size_t)MROWS * 3 * DMODEL * 2);
  bf16_t* ctxb = (bf16_t*)alloc((size_t)MROWS * DMODEL * 2);
  bf16_t* membb = (bf16_t*)alloc((size_t)MROWS * DMODEL * 2);
  bf16_t* ffh = (bf16_t*)alloc((size_t)MROWS * DFFN * 2);
  bf16_t* wA = (bf16_t*)alloc((size_t)4 * DMODEL * DMODEL * 2);
  bf16_t* wF1 = (bf16_t*)alloc((size_t)DFFN * DMODEL * 2);
  bf16_t* wF2 = (bf16_t*)alloc((size_t)DFFN * DMODEL * 2);

  const long PSTR = (long)MROWS * DMODEL;

  auto gemm = [&](const bf16_t* A, const bf16_t* Bm, const float* bias,
                  const float* resid, float* oF, bf16_t* oB, int M, int N, int K,
                  int lda, int ldb, int ldc, int act, int ksplit) {
    GP p{A, Bm, bias, resid, oF, oB, M, N, K, lda, ldb, ldc, PSTR, act, ksplit};
    dim3 g((unsigned)(M / 128), (unsigned)(N / 128), (unsigned)ksplit);
    gemm_kernel<<<g, 256, 0, stream>>>(p);
  };

  const long WSZ = (long)DMODEL * DMODEL;

  emb_kernel<<<MROWS, 256, 0, stream>>>(tgt, embt, res);
  cvt_kernel<<<(MROWS * DMODEL / 4 + 255) / 256, 256, 0, stream>>>(memb, membb,
                                                                   MROWS * DMODEL / 4);
  ln_kernel<<<MROWS, 256, 0, stream>>>(res, ln_g, ln_b, xb, nullptr);

  for (int l = 0; l < NLAYER; ++l) {
    const float* saw = sa_w + (long)l * 4 * WSZ;
    const float* sab = sa_b + (long)l * 4 * DMODEL;
    const float* caw = ca_w + (long)l * 4 * WSZ;
    const float* cab = ca_b + (long)l * 4 * DMODEL;

    // ======== self-attention ========   (xb = ln1(res) already available)
    cvt_kernel<<<(int)((WSZ + 255) / 256), 256, 0, stream>>>(saw, wA, (int)WSZ);
    gemm(xb, wA, sab, nullptr, nullptr, qkvb, MROWS, 3 * DMODEL, DMODEL,
         DMODEL, DMODEL, 3 * DMODEL, 0, 1);
    attn_kernel<<<dim3(SEQ / QT, BATCH * NHEAD), 256, 0, stream>>>(qkvb, tgt, ctxb, 1);
    gemm(ctxb, wA + 3 * WSZ, nullptr, nullptr, parts, nullptr, MROWS, DMODEL, DMODEL,
         DMODEL, DMODEL, DMODEL, 0, 2);
    reduce_ln_kernel<<<MROWS, 256, 0, stream>>>(parts, PSTR, 2, sab + 3 * DMODEL, res,
                                                ln_g + (l * 3 + 1) * DMODEL,
                                                ln_b + (l * 3 + 1) * DMODEL, xb, nullptr);

    // ======== cross-attention ========  (xb = ln2)
    cvt_kernel<<<(int)((WSZ + 255) / 256), 256, 0, stream>>>(caw, wA, (int)WSZ);
    gemm(xb, wA, nullptr, nullptr, parts, nullptr, MROWS, DMODEL, DMODEL,
         DMODEL, DMODEL, DMODEL, 0, 2);
    reduce_cvtq_kernel<<<MROWS, 256, 0, stream>>>(parts, PSTR, 2, cab, qkvb);
    gemm(membb, wA + WSZ, cab + DMODEL, nullptr, nullptr, qkvb + DMODEL, MROWS,
         2 * DMODEL, DMODEL, DMODEL, DMODEL, 3 * DMODEL, 0, 1);
    attn_kernel<<<dim3(SEQ / QT, BATCH * NHEAD), 256, 0, stream>>>(qkvb, srct, ctxb, 0);
    gemm(ctxb, wA + 3 * WSZ, nullptr, nullptr, parts, nullptr, MROWS, DMODEL, DMODEL,
         DMODEL, DMODEL, DMODEL, 0, 2);
    reduce_ln_kernel<<<MROWS, 256, 0, stream>>>(parts, PSTR, 2, cab + 3 * DMODEL, res,
                                                ln_g + (l * 3 + 2) * DMODEL,
                                                ln_b + (l * 3 + 2) * DMODEL, xb, nullptr);

    // ======== FFN ========  (xb = ln3)
    cvt_kernel<<<(int)((DFFN * (long)DMODEL / 4 + 255) / 256), 256, 0, stream>>>(
        ff_w1 + (long)l * DFFN * DMODEL, wF1, (int)(DFFN * (long)DMODEL / 4));
    cvt_kernel<<<(int)((DFFN * (long)DMODEL / 4 + 255) / 256), 256, 0, stream>>>(
        ff_w2 + (long)l * DFFN * DMODEL, wF2, (int)(DFFN * (long)DMODEL / 4));
    gemm(xb, wF1, ff_b1 + (long)l * DFFN, nullptr, nullptr, ffh, MROWS, DFFN,
         DMODEL, DMODEL, DMODEL, DFFN, 1, 1);
    gemm(ffh, wF2, nullptr, nullptr, parts, nullptr, MROWS, DMODEL, DFFN,
         DFFN, DFFN, DMODEL, 0, 2);
    if (l < NLAYER - 1) {
      reduce_ln_kernel<<<MROWS, 256, 0, stream>>>(parts, PSTR, 2, ff_b2 + (long)l * DMODEL,
                                                  res, ln_g + ((l + 1) * 3) * DMODEL,
                                                  ln_b + ((l + 1) * 3) * DMODEL, xb, nullptr);
    } else {
      reduce_ln_kernel<<<MROWS, 256, 0, stream>>>(parts, PSTR, 2, ff_b2 + (long)l * DMODEL,
                                                  res, out_g, out_b, nullptr, out);
    }
  }
}